// Round 14
// baseline (149.684 us; speedup 1.0000x reference)
//
#include <hip/hip_runtime.h>
#include <hip/hip_bf16.h>
#include <hip/hip_cooperative_groups.h>

namespace cg = cooperative_groups;

#define N_TOTAL 4096
#define C_DIM 256
#define K_NEG 128
#define HW 1024
#define TEMP_INV (1.0f / 0.07f)

typedef _Float16 h8 __attribute__((ext_vector_type(8)));
typedef _Float16 h2 __attribute__((ext_vector_type(2)));

// ---------------------------------------------------------------------------
// Single cooperative kernel, 256 blocks x 512 threads, launch_bounds(512,2)
// -> 1 block/CU guaranteed co-resident (r13 failed at the 2-blocks/CU
// occupancy cliff and never launched). Fuses all three stages; grid.sync()
// replaces 2 kernel-boundary gaps.
//   Phase 1: r9's proven 16-row normalize+transpose, 2 groups per block.
//            q rows carry 1/T; k rows plain normalized f16.
//   Phase 2: r12's proven per-wave InfoNCE body, 2 rows per wave.
//   Phase 3: block 0 reduces 4096 losses -> mean.
// ---------------------------------------------------------------------------
__global__ __launch_bounds__(512, 2) void fused_kernel(
    const float* __restrict__ fq, const float* __restrict__ fk,
    const int* __restrict__ neg, _Float16* __restrict__ qh,
    _Float16* __restrict__ kh, float* __restrict__ loss_buf,
    float* __restrict__ out) {
  const int t = threadIdx.x;
  const int bid = blockIdx.x;

  __shared__ float tile[2][16][C_DIM + 1];   // 32.9 KB
  __shared__ float red[2][16][17];
  __shared__ float sinv[2][16];
  __shared__ float red3[8];

  // ===================== Phase 1: normalize + transpose ====================
  {
    const int g = t >> 8, u = t & 255;        // group, local tid
    const int cid = bid * 2 + g;              // 0..511
    const int tensor = cid >> 8;              // 0=q, 1=k
    const int chunk = cid & 255;              // 16-row chunk
    const int n0 = chunk * 16;
    const int b = n0 / HW, s0 = n0 % HW;
    const float* base = (tensor ? fk : fq) + (size_t)b * C_DIM * HW + s0;
    _Float16* outp = tensor ? kh : qh;
    const float scale_extra = tensor ? 1.0f : TEMP_INV;  // fold 1/T into q

    // load: thread u = channel; 16 spatial floats as 4x float4
    {
      const float* src = base + (size_t)u * HW;
#pragma unroll
      for (int p = 0; p < 4; ++p) {
        const float4 v = *(const float4*)(src + p * 4);
        tile[g][p * 4 + 0][u] = v.x;
        tile[g][p * 4 + 1][u] = v.y;
        tile[g][p * 4 + 2][u] = v.z;
        tile[g][p * 4 + 3][u] = v.w;
      }
    }
    __syncthreads();

    // sum of squares per row: 16 threads/row x 16 channels each
    {
      const int s = u & 15, cg16 = u >> 4;
      float acc = 0.f;
#pragma unroll
      for (int i = 0; i < 16; ++i) {
        float v = tile[g][s][cg16 * 16 + i];
        acc = fmaf(v, v, acc);
      }
      red[g][s][cg16] = acc;
    }
    __syncthreads();
    if (u < 16) {
      float tot = 0.f;
#pragma unroll
      for (int j = 0; j < 16; ++j) tot += red[g][u][j];
      sinv[g][u] = scale_extra / fmaxf(sqrtf(tot), 1e-12f);  // eps = 1e-12
    }
    __syncthreads();

    // write normalized f16: thread u -> row u&15, 16-ch chunk u>>4 (2x16B)
    {
      const int s = u & 15, c16 = u >> 4;
      const float inv = sinv[g][s];
      h8 o0, o1;
#pragma unroll
      for (int j = 0; j < 8; ++j)
        o0[j] = (_Float16)(tile[g][s][c16 * 16 + j] * inv);
#pragma unroll
      for (int j = 0; j < 8; ++j)
        o1[j] = (_Float16)(tile[g][s][c16 * 16 + 8 + j] * inv);
      h8* dst = (h8*)(outp + (size_t)(n0 + s) * C_DIM + c16 * 16);
      dst[0] = o0;
      dst[1] = o1;
    }
  }

  cg::this_grid().sync();

  // ===================== Phase 2: per-wave InfoNCE (2 rows/wave) ===========
  {
    const int w = t >> 6, lane = t & 63;
    const int sub = lane & 7;            // lane within 8-lane unit
    const int unit = lane >> 3;          // 0..7

    union H { h8 v; h2 p[4]; };

#pragma unroll
    for (int rr = 0; rr < 2; ++rr) {
      const int n = bid * 16 + rr * 8 + w;

      const h8* qrow = (const h8*)(qh + (size_t)n * C_DIM);
      h8 qv[4];
#pragma unroll
      for (int i = 0; i < 4; ++i) qv[i] = qrow[i * 8 + sub];
      const h8* kpr = (const h8*)(kh + (size_t)n * C_DIM);
      h8 kp[4];
#pragma unroll
      for (int i = 0; i < 4; ++i) kp[i] = kpr[i * 8 + sub];

      const int* nrow = neg + (size_t)n * K_NEG + unit * 16;

      float m = -1e30f, s = 0.f;
#pragma unroll 4
      for (int j = 0; j < 16; ++j) {
        const int x = nrow[j];
        const int r = x + (x >= n ? 1 : 0);  // self-exclusion shift
        const h8* kr = (const h8*)(kh + (size_t)r * C_DIM);
        float a0 = 0.f, a1 = 0.f;
#pragma unroll
        for (int i = 0; i < 4; ++i) {
          H a; a.v = qv[i];
          H b; b.v = kr[i * 8 + sub];        // 128B contiguous per unit
          a0 = __builtin_amdgcn_fdot2(b.p[0], a.p[0], a0, false);
          a1 = __builtin_amdgcn_fdot2(b.p[1], a.p[1], a1, false);
          a0 = __builtin_amdgcn_fdot2(b.p[2], a.p[2], a0, false);
          a1 = __builtin_amdgcn_fdot2(b.p[3], a.p[3], a1, false);
        }
        float acc = a0 + a1;
        acc += __shfl_xor(acc, 1);
        acc += __shfl_xor(acc, 2);
        acc += __shfl_xor(acc, 4);
        const float mn = fmaxf(m, acc);      // online LSE (unit-uniform)
        s = s * __expf(m - mn) + __expf(acc - mn);
        m = mn;
      }

      float lp;
      {
        float a0 = 0.f, a1 = 0.f;
#pragma unroll
        for (int i = 0; i < 4; ++i) {
          H a; a.v = qv[i];
          H b; b.v = kp[i];
          a0 = __builtin_amdgcn_fdot2(b.p[0], a.p[0], a0, false);
          a1 = __builtin_amdgcn_fdot2(b.p[1], a.p[1], a1, false);
          a0 = __builtin_amdgcn_fdot2(b.p[2], a.p[2], a0, false);
          a1 = __builtin_amdgcn_fdot2(b.p[3], a.p[3], a1, false);
        }
        float acc = a0 + a1;
        acc += __shfl_xor(acc, 1);
        acc += __shfl_xor(acc, 2);
        acc += __shfl_xor(acc, 4);
        lp = acc;
      }

#pragma unroll
      for (int off = 8; off <= 32; off <<= 1) {
        const float mo = __shfl_xor(m, off);
        const float so = __shfl_xor(s, off);
        const float mn = fmaxf(m, mo);
        s = s * __expf(m - mn) + so * __expf(mo - mn);
        m = mn;
      }
      const float M = fmaxf(m, lp);
      const float stot = s * __expf(m - M) + __expf(lp - M);
      if (lane == 0) loss_buf[n] = M + __logf(stot) - lp;
    }
  }

  cg::this_grid().sync();

  // ===================== Phase 3: mean (block 0) ===========================
  if (bid == 0) {
    const float4 v0 = ((const float4*)loss_buf)[2 * t];
    const float4 v1 = ((const float4*)loss_buf)[2 * t + 1];
    float s = ((v0.x + v0.y) + (v0.z + v0.w)) +
              ((v1.x + v1.y) + (v1.z + v1.w));
#pragma unroll
    for (int off = 32; off; off >>= 1) s += __shfl_xor(s, off);
    if ((t & 63) == 0) red3[t >> 6] = s;
    __syncthreads();
    if (t < 8) {
      float x = red3[t];
#pragma unroll
      for (int off = 4; off; off >>= 1) x += __shfl_xor(x, off);
      if (t == 0) out[0] = x * (1.0f / N_TOTAL);
    }
  }
}

extern "C" void kernel_launch(void* const* d_in, const int* in_sizes, int n_in,
                              void* d_out, int out_size, void* d_ws,
                              size_t ws_size, hipStream_t stream) {
  const float* fq = (const float*)d_in[0];
  const float* fk = (const float*)d_in[1];
  const int* neg = (const int*)d_in[2];
  float* out = (float*)d_out;

  _Float16* qh = (_Float16*)d_ws;                            // 2 MiB
  _Float16* kh = qh + (size_t)N_TOTAL * C_DIM;               // 2 MiB
  float* loss_buf = (float*)(kh + (size_t)N_TOTAL * C_DIM);  // 16 KiB

  void* args[] = {(void*)&fq, (void*)&fk, (void*)&neg, (void*)&qh,
                  (void*)&kh, (void*)&loss_buf, (void*)&out};
  hipLaunchCooperativeKernel((const void*)fused_kernel, dim3(256), dim3(512),
                             args, 0, stream);
}

// Round 15
// 80.193 us; speedup vs baseline: 1.8665x; 1.8665x over previous
//
#include <hip/hip_runtime.h>
#include <hip/hip_bf16.h>

#define N_TOTAL 4096
#define C_DIM 256
#define K_NEG 128
#define HW 1024
#define TEMP_INV (1.0f / 0.07f)

typedef _Float16 h8 __attribute__((ext_vector_type(8)));
typedef float fv2 __attribute__((ext_vector_type(2)));

// ---------------------------------------------------------------------------
// Kernel 1 (r11 proven): normalize + transpose, single pass.
// q -> f16 rows with 1/T folded; k -> fp8 e4m3 rows (half gather bytes).
// Block 0 also zeroes out[0] (timed replays re-poison d_out with 0xAA;
// kernel order on the stream guarantees the zero lands before nce's atomics).
// ---------------------------------------------------------------------------
__global__ __launch_bounds__(256) void norm_tr_kernel(
    const float* __restrict__ fq, const float* __restrict__ fk,
    _Float16* __restrict__ qh, unsigned char* __restrict__ kh8,
    float* __restrict__ out) {
  if (blockIdx.x == 0 && threadIdx.x == 0) out[0] = 0.f;

  const int bid = blockIdx.x;
  const int tensor = bid >> 8;         // 0=q, 1=k
  const int chunk = bid & 255;         // 16-row chunk
  const int n0 = chunk * 16;
  const int b = n0 / HW, s0 = n0 % HW;
  const float* base = (tensor ? fk : fq) + (size_t)b * C_DIM * HW + s0;

  const int t = threadIdx.x;
  __shared__ float tile[16][C_DIM + 1];
  __shared__ float red[16][17];
  __shared__ float sinv[16];

  {
    const float* src = base + (size_t)t * HW;
#pragma unroll
    for (int p = 0; p < 4; ++p) {
      const float4 v = *(const float4*)(src + p * 4);
      tile[p * 4 + 0][t] = v.x;
      tile[p * 4 + 1][t] = v.y;
      tile[p * 4 + 2][t] = v.z;
      tile[p * 4 + 3][t] = v.w;
    }
  }
  __syncthreads();

  {
    const int s = t & 15, cg = t >> 4;
    float acc = 0.f;
#pragma unroll
    for (int i = 0; i < 16; ++i) {
      float v = tile[s][cg * 16 + i];
      acc = fmaf(v, v, acc);
    }
    red[s][cg] = acc;
  }
  __syncthreads();
  if (t < 16) {
    float tot = 0.f;
#pragma unroll
    for (int g = 0; g < 16; ++g) tot += red[t][g];
    const float scale_extra = tensor ? 1.0f : TEMP_INV;  // fold 1/T into q
    sinv[t] = scale_extra / fmaxf(sqrtf(tot), 1e-12f);   // eps = 1e-12
  }
  __syncthreads();

  if (tensor == 0) {
    const int s = t & 15, c16 = t >> 4;
    const float inv = sinv[s];
    h8 o0, o1;
#pragma unroll
    for (int j = 0; j < 8; ++j) o0[j] = (_Float16)(tile[s][c16 * 16 + j] * inv);
#pragma unroll
    for (int j = 0; j < 8; ++j)
      o1[j] = (_Float16)(tile[s][c16 * 16 + 8 + j] * inv);
    h8* dst = (h8*)(qh + (size_t)(n0 + s) * C_DIM + c16 * 16);
    dst[0] = o0;
    dst[1] = o1;
  } else {
    const int s = t >> 4, c16 = t & 15;   // 16 lanes cover one 256B fp8 row
    const float inv = sinv[s];
    uint4 W;
#pragma unroll
    for (int p = 0; p < 4; ++p) {
      const int e = c16 * 16 + p * 4;
      unsigned u = 0;
      u = __builtin_amdgcn_cvt_pk_fp8_f32(tile[s][e + 0] * inv,
                                          tile[s][e + 1] * inv, u, false);
      u = __builtin_amdgcn_cvt_pk_fp8_f32(tile[s][e + 2] * inv,
                                          tile[s][e + 3] * inv, u, true);
      ((unsigned*)&W)[p] = u;
    }
    ((uint4*)(kh8 + (size_t)(n0 + s) * C_DIM))[c16] = W;
  }
}

// ---------------------------------------------------------------------------
// Kernel 2: per-WAVE InfoNCE + block-level mean contribution.
// 256 blocks x 1024 threads (16 waves); wave = one row (4 waves/SIMD).
// Unit (8 lanes) processes 16 negatives with online LSE; fp8 k rows decoded
// via HW cvt_pk_f32_fp8 (r11 path). Block reduces its 16 losses in LDS and
// issues ONE atomicAdd -> 256-deep chain (~1-2us effective, hidden by
// staggered completion), replacing the reduce kernel + its launch gap.
// ---------------------------------------------------------------------------
__global__ __launch_bounds__(1024) void nce_kernel(
    const _Float16* __restrict__ qh, const unsigned char* __restrict__ kh8,
    const int* __restrict__ neg, float* __restrict__ out) {
  const int t = threadIdx.x;
  const int w = t >> 6, lane = t & 63;
  const int sub = lane & 7;            // lane within 8-lane unit
  const int unit = lane >> 3;          // 0..7
  const int n = blockIdx.x * 16 + w;

  __shared__ float wloss[16];

  // q row (1/T folded): lane sub owns f32 elems [sub*16,+16) and
  // [128+sub*16,+16), matching the fp8 uint4 chunk layout.
  const h8* qrow = (const h8*)(qh + (size_t)n * C_DIM);
  h8 qv[4];
  qv[0] = qrow[2 * sub];
  qv[1] = qrow[2 * sub + 1];
  qv[2] = qrow[16 + 2 * sub];
  qv[3] = qrow[16 + 2 * sub + 1];
  float qf[32];
#pragma unroll
  for (int i = 0; i < 4; ++i)
#pragma unroll
    for (int e = 0; e < 8; ++e) qf[i * 8 + e] = (float)qv[i][e];

  // positive k row (fp8): lane sub reads uint4 chunks sub and 8+sub
  const uint4* kpr = (const uint4*)(kh8 + (size_t)n * C_DIM);
  uint4 kp0 = kpr[sub], kp1 = kpr[8 + sub];

  // fp8 word dot: 16 elems of U against qf[base..base+16)
  auto dot16 = [&](const uint4& U, int base, float& acc) {
#pragma unroll
    for (int p = 0; p < 4; ++p) {
      const unsigned u = ((const unsigned*)&U)[p];
      fv2 ab = __builtin_amdgcn_cvt_pk_f32_fp8(u, false);
      fv2 cd = __builtin_amdgcn_cvt_pk_f32_fp8(u, true);
      acc = fmaf(ab.x, qf[base + p * 4 + 0], acc);
      acc = fmaf(ab.y, qf[base + p * 4 + 1], acc);
      acc = fmaf(cd.x, qf[base + p * 4 + 2], acc);
      acc = fmaf(cd.y, qf[base + p * 4 + 3], acc);
    }
  };

  const int* nrow = neg + (size_t)n * K_NEG + unit * 16;

  float m = -1e30f, s = 0.f;
#pragma unroll 2
  for (int j = 0; j < 16; ++j) {
    const int x = nrow[j];               // broadcast within unit
    const int r = x + (x >= n ? 1 : 0);  // self-exclusion shift
    const uint4* kr = (const uint4*)(kh8 + (size_t)r * C_DIM);
    const uint4 k0 = kr[sub], k1 = kr[8 + sub];
    float acc = 0.f;
    dot16(k0, 0, acc);
    dot16(k1, 16, acc);
    acc += __shfl_xor(acc, 1);
    acc += __shfl_xor(acc, 2);
    acc += __shfl_xor(acc, 4);
    const float mn = fmaxf(m, acc);      // online LSE (unit-uniform)
    s = s * __expf(m - mn) + __expf(acc - mn);
    m = mn;
  }

  // positive logit
  float lp;
  {
    float acc = 0.f;
    dot16(kp0, 0, acc);
    dot16(kp1, 16, acc);
    acc += __shfl_xor(acc, 1);
    acc += __shfl_xor(acc, 2);
    acc += __shfl_xor(acc, 4);
    lp = acc;
  }

  // merge the 8 units' (m,s) pairs across the wave
#pragma unroll
  for (int off = 8; off <= 32; off <<= 1) {
    const float mo = __shfl_xor(m, off);
    const float so = __shfl_xor(s, off);
    const float mn = fmaxf(m, mo);
    s = s * __expf(m - mn) + so * __expf(mo - mn);
    m = mn;
  }
  const float M = fmaxf(m, lp);
  const float stot = s * __expf(m - M) + __expf(lp - M);
  if (lane == 0) wloss[w] = M + __logf(stot) - lp;
  __syncthreads();

  // block: reduce 16 wave-losses, one atomicAdd per block
  if (t < 16) {
    float v = wloss[t];
#pragma unroll
    for (int off = 8; off; off >>= 1) v += __shfl_xor(v, off);
    if (t == 0) atomicAdd(out, v * (1.0f / N_TOTAL));
  }
}

extern "C" void kernel_launch(void* const* d_in, const int* in_sizes, int n_in,
                              void* d_out, int out_size, void* d_ws,
                              size_t ws_size, hipStream_t stream) {
  const float* fq = (const float*)d_in[0];
  const float* fk = (const float*)d_in[1];
  const int* neg = (const int*)d_in[2];
  float* out = (float*)d_out;

  _Float16* qh = (_Float16*)d_ws;                               // 2 MiB
  unsigned char* kh8 = (unsigned char*)(qh + (size_t)N_TOTAL * C_DIM); // 1 MiB

  hipLaunchKernelGGL(norm_tr_kernel, dim3(512), dim3(256), 0, stream,
                     fq, fk, qh, kh8, out);
  hipLaunchKernelGGL(nce_kernel, dim3(N_TOTAL / 16), dim3(1024), 0, stream,
                     qh, kh8, neg, out);
}